// Round 10
// baseline (1155.702 us; speedup 1.0000x reference)
//
#include <hip/hip_runtime.h>
#include <hip/hip_bf16.h>

typedef unsigned short u16;
typedef unsigned int u32;

static __device__ __forceinline__ float us2f(u16 u) {
    return __uint_as_float(((u32)u) << 16);
}
static __device__ __forceinline__ u16 f2bu(float f) {  // RNE
    u32 u = __float_as_uint(f);
    return (u16)((u + 0x7fffu + ((u >> 16) & 1u)) >> 16);
}

typedef __attribute__((ext_vector_type(8))) __bf16 bf16x8;
typedef __attribute__((ext_vector_type(4))) float f32x4;

__global__ void fill_sentinel(float* out, int n, float val) {
    int g = blockIdx.x * 256 + threadIdx.x;
    if (g < n) out[g] = val;
}

// ============================================================
// Kernel 0: conv1 weights f32 [c][j] -> bf16 [j][c] (one-time)
// ============================================================
__global__ __launch_bounds__(256) void conv_c1wb(const float* __restrict__ w,
                                                 u16* __restrict__ wb)
{
    const int j = blockIdx.x, c = threadIdx.x;   // 81 x 256
    wb[j * 256 + c] = f2bu(w[c * 81 + j]);
}

// ============================================================
// Kernel 1: conv1 9x9 s1 + bias + relu -> h NHWC bf16 [B][20][20][256]
// ============================================================
__global__ __launch_bounds__(256) void conv1_kernel(const float* __restrict__ x,
    const u16* __restrict__ wb, const float* __restrict__ bias, u16* __restrict__ h)
{
    __shared__ float xs[784];
    __shared__ u16 wl[81 * 256];   // [tap][channel] bf16
    const int b = blockIdx.x >> 2, g = blockIdx.x & 3;
    const int c = threadIdx.x;
    for (int idx = c; idx < 784; idx += 256) xs[idx] = x[b * 784 + idx];
    for (int idx = c; idx < 20736; idx += 256) wl[idx] = wb[idx];
    __syncthreads();
    const float bv = bias[c];
    #pragma unroll 1
    for (int iy = g * 5; iy < g * 5 + 5; ++iy) {
        float acc[20];
        #pragma unroll
        for (int i = 0; i < 20; ++i) acc[i] = bv;
        #pragma unroll 1
        for (int dy = 0; dy < 9; ++dy) {
            float xr[28];
            const float4* xrow = reinterpret_cast<const float4*>(&xs[(iy + dy) * 28]);
            #pragma unroll
            for (int i = 0; i < 7; ++i) {
                float4 v = xrow[i];
                xr[4*i] = v.x; xr[4*i+1] = v.y; xr[4*i+2] = v.z; xr[4*i+3] = v.w;
            }
            #pragma unroll
            for (int dx = 0; dx < 9; ++dx) {
                const float wv = us2f(wl[(dy * 9 + dx) * 256 + c]);
                #pragma unroll
                for (int ix = 0; ix < 20; ++ix) acc[ix] += xr[ix + dx] * wv;
            }
        }
        u16* hp = h + ((b * 20 + iy) * 20) * 256 + c;
        #pragma unroll
        for (int ix = 0; ix < 20; ++ix) hp[ix * 256] = f2bu(fmaxf(acc[ix], 0.f));
    }
}

// ============================================================
// Kernel 2: transpose prim_w f32 [n][c][kyx] -> wT2 bf16 [n][kyx][c]
// ============================================================
__global__ __launch_bounds__(256) void transpose_primw(const float* __restrict__ w,
                                                       u16* __restrict__ wt)
{
    __shared__ u16 wl[81 * 258];
    const int n = blockIdx.x, tid = threadIdx.x;
    const float* ws = w + (size_t)n * 20736;
    for (int idx = tid; idx < 20736; idx += 256) {
        const int cc = idx / 81, kk = idx - cc * 81;
        wl[kk * 258 + cc] = f2bu(ws[idx]);
    }
    __syncthreads();
    u16* wo = wt + (size_t)n * 20736;
    for (int q = tid; q < 20736; q += 256)
        wo[q] = wl[(q >> 8) * 258 + (q & 255)];
}

// ============================================================
// Kernel 3: dw f32 -> bf16 in two layouts
// ============================================================
__global__ __launch_bounds__(256) void conv_dwb(const float* __restrict__ dw,
    u16* __restrict__ dwb_t, u16* __restrict__ dwb_a)
{
    const int g = blockIdx.x * 256 + threadIdx.x;   // 1,474,560
    const float v = dw[g];
    const u16 bv = f2bu(v);
    dwb_t[g] = bv;
    const int i = g / 1280, rem = g % 1280;
    const int a = rem / 160, ot = rem % 160;
    dwb_a[((size_t)i * 160 + ot) * 8 + a] = bv;
}

// ============================================================
// Kernel 4: primary-caps implicit GEMM, NO-LDS variant.
// Both A and B fragments are 16B-contiguous in global -> direct VGPR loads,
// no __syncthreads, register double-buffer (prefetch kt+1 during kt MFMA).
// grid (144, 8), block 256 (4 waves, 2x2 of 64x64). f32 atomics into pm.
// ============================================================
__global__ __launch_bounds__(256) void prim_gemm_noLDS(const u16* __restrict__ h,
    const u16* __restrict__ wT, float* __restrict__ pm)
{
    const int tid = threadIdx.x;
    const int split = blockIdx.y;                  // k in [split*2592, +2592)
    const int mt = blockIdx.x % 72, nt = blockIdx.x / 72;
    const int mBase = mt * 128, nBase = nt * 128;
    const int lane = tid & 63;
    const int wvi = tid >> 6, wm = wvi >> 1, wn = wvi & 1;
    const int lcol = lane & 15, lquad = lane >> 4;

    // A fragment pixel bases (m = mBase + wm*64 + i*16 + lcol)
    int aBase[4];
    #pragma unroll
    for (int i = 0; i < 4; ++i) {
        const int m = mBase + wm * 64 + i * 16 + lcol;
        const int bb = m / 36, r = m % 36;
        aBase[i] = ((bb * 20 + 2 * (r / 6)) * 20 + 2 * (r % 6)) * 256 + lquad * 8;
    }
    // B fragment row bases (n = nBase + wn*64 + j*16 + lcol)
    size_t bBase[4];
    #pragma unroll
    for (int j = 0; j < 4; ++j)
        bBase[j] = (size_t)(nBase + wn * 64 + j * 16 + lcol) * 20736 + lquad * 8;

    int kglob = split * 2592;
    int ky = kglob / 2304; int krem = kglob - ky * 2304;
    int kx = krem >> 8, c0 = krem & 255;

    f32x4 acc[4][4];
    #pragma unroll
    for (int i = 0; i < 4; ++i)
        #pragma unroll
        for (int j = 0; j < 4; ++j) acc[i][j] = (f32x4){0.f, 0.f, 0.f, 0.f};

    bf16x8 af0[4], bf0[4];
    {
        const int koffA = (ky * 20 + kx) * 256 + c0;
        #pragma unroll
        for (int i = 0; i < 4; ++i)
            af0[i] = *reinterpret_cast<const bf16x8*>(h + aBase[i] + koffA);
        #pragma unroll
        for (int j = 0; j < 4; ++j)
            bf0[j] = *reinterpret_cast<const bf16x8*>(wT + bBase[j] + kglob);
    }

    #pragma unroll 1
    for (int kt = 0; kt < 80; ++kt) {
        // advance k counters to kt+1
        kglob += 32; c0 += 32;
        if (c0 == 256) { c0 = 0; if (++kx == 9) { kx = 0; ++ky; } }
        const int koffA = (ky * 20 + kx) * 256 + c0;
        bf16x8 af1[4], bf1[4];
        #pragma unroll
        for (int i = 0; i < 4; ++i)
            af1[i] = *reinterpret_cast<const bf16x8*>(h + aBase[i] + koffA);
        #pragma unroll
        for (int j = 0; j < 4; ++j)
            bf1[j] = *reinterpret_cast<const bf16x8*>(wT + bBase[j] + kglob);
        #pragma unroll
        for (int i = 0; i < 4; ++i)
            #pragma unroll
            for (int j = 0; j < 4; ++j)
                acc[i][j] = __builtin_amdgcn_mfma_f32_16x16x32_bf16(af0[i], bf0[j], acc[i][j], 0, 0, 0);
        #pragma unroll
        for (int i = 0; i < 4; ++i) { af0[i] = af1[i]; bf0[i] = bf1[i]; }
    }
    #pragma unroll
    for (int i = 0; i < 4; ++i)
        #pragma unroll
        for (int j = 0; j < 4; ++j)
            acc[i][j] = __builtin_amdgcn_mfma_f32_16x16x32_bf16(af0[i], bf0[j], acc[i][j], 0, 0, 0);

    #pragma unroll
    for (int i = 0; i < 4; ++i) {
        const int mrow = mBase + wm * 64 + i * 16 + lquad * 4;
        #pragma unroll
        for (int j = 0; j < 4; ++j) {
            const int ncol = nBase + wn * 64 + j * 16 + lcol;
            #pragma unroll
            for (int r = 0; r < 4; ++r)
                unsafeAtomicAdd(&pm[(size_t)(mrow + r) * 256 + ncol], acc[i][j][r]);
        }
    }
}

// ============================================================
// Kernel 5: in-place /32 + prim_b + squash over 8-atom groups (row-local)
// ============================================================
__global__ __launch_bounds__(256) void squash_kernel(float* __restrict__ pm,
    const float* __restrict__ pb)
{
    const int m = blockIdx.x, t = threadIdx.x;
    float pre = pm[(size_t)m * 256 + t] * (1.f / 32.f) + pb[t];
    float sq = pre * pre;
    sq += __shfl_xor(sq, 1); sq += __shfl_xor(sq, 2); sq += __shfl_xor(sq, 4);
    float scale = (sq / (1.f + sq)) * rsqrtf(sq + 1e-9f);
    pm[(size_t)m * 256 + t] = pre * scale;
}

// ============================================================
// Kernel 6: routing preact partial. grid (18 i-chunks of 64, 32 b-groups).
// 8 b's per block; dwb_a [i][o][t][a] uint4 loads, unroll 4.
// ============================================================
__global__ __launch_bounds__(256) void routing_act_part(const float* __restrict__ x3m,
    const u16* __restrict__ dwb_a, const float* __restrict__ logits,
    float* __restrict__ preactD, int uniform)
{
    __shared__ float x3s[4096];    // [b][il][a] 16 KB
    __shared__ float rs[5120];     // [b][il][o] 20 KB
    const int c = blockIdx.x, bg = blockIdx.y;
    const int tid = threadIdx.x;
    for (int q = tid; q < 4096; q += 256) {
        const int b_l = q >> 9, rest = q & 511, il = rest >> 3, a = rest & 7;
        const int i = c * 64 + il, cap = i / 36, p = i - cap * 36;
        x3s[q] = x3m[((size_t)(bg * 8 + b_l) * 36 + p) * 256 + cap * 8 + a];
    }
    if (!uniform) {
        for (int q = tid; q < 512; q += 256) {
            const int b_l = q >> 6, il = q & 63;
            const int i = c * 64 + il;
            const float* lg = &logits[((size_t)(bg * 8 + b_l) * 1152 + i) * 10];
            float l[10]; float mx = -1e30f;
            #pragma unroll
            for (int k = 0; k < 10; ++k) { l[k] = lg[k]; mx = fmaxf(mx, l[k]); }
            float s = 0.f;
            #pragma unroll
            for (int k = 0; k < 10; ++k) { l[k] = __expf(l[k] - mx); s += l[k]; }
            const float inv = 1.f / s;
            #pragma unroll
            for (int k = 0; k < 10; ++k) rs[(b_l * 64 + il) * 10 + k] = l[k] * inv;
        }
    }
    __syncthreads();
    if (tid < 160) {
        const int ot = tid, o = tid >> 4;
        float preg[8];
        #pragma unroll
        for (int b_l = 0; b_l < 8; ++b_l) preg[b_l] = 0.f;
        #pragma unroll 4
        for (int il = 0; il < 64; ++il) {
            const int i = c * 64 + il;
            const uint4 dq = *reinterpret_cast<const uint4*>(
                &dwb_a[((size_t)i * 160 + ot) * 8]);
            const u32 du[4] = {dq.x, dq.y, dq.z, dq.w};
            float dv[8];
            #pragma unroll
            for (int q = 0; q < 4; ++q) {
                dv[2 * q]     = __uint_as_float(du[q] << 16);
                dv[2 * q + 1] = __uint_as_float(du[q] & 0xffff0000u);
            }
            #pragma unroll
            for (int b_l = 0; b_l < 8; ++b_l) {
                const float* xp = &x3s[(b_l * 64 + il) * 8];
                float v = 0.f;
                #pragma unroll
                for (int a = 0; a < 8; ++a) v += xp[a] * dv[a];
                const float r = uniform ? 0.1f : rs[(b_l * 64 + il) * 10 + o];
                preg[b_l] += r * v;
            }
        }
        #pragma unroll
        for (int b_l = 0; b_l < 8; ++b_l)
            unsafeAtomicAdd(&preactD[(size_t)(bg * 8 + b_l) * 160 + tid], preg[b_l]);
    }
}

// ============================================================
// Kernel 7: preactD + digit_b -> squash -> act (+digit out)
// ============================================================
__global__ __launch_bounds__(192) void routing_squash(const float* __restrict__ preactD,
    const float* __restrict__ db, float* __restrict__ act, float* __restrict__ dout)
{
    const int b = blockIdx.x, tid = threadIdx.x;
    if (tid < 160) {
        float pre = preactD[(size_t)b * 160 + tid] + db[tid];
        float sq = pre * pre;
        sq += __shfl_xor(sq, 1); sq += __shfl_xor(sq, 2);
        sq += __shfl_xor(sq, 4); sq += __shfl_xor(sq, 8);
        float scale = (sq / (1.f + sq)) * rsqrtf(sq + 1e-9f);
        float a = pre * scale;
        act[(size_t)b * 160 + tid] = a;
        if (dout) dout[(size_t)b * 160 + tid] = a;
    }
}

// ============================================================
// Kernel 8: logits update. grid (18, 32), block 128 = 64 i x 2 o-halves.
// ============================================================
__global__ __launch_bounds__(128) void routing_upd_part(const float* __restrict__ x3m,
    const u16* __restrict__ dwb_t, const float* __restrict__ act,
    float* __restrict__ logits, int first)
{
    __shared__ float x3s[4096];
    __shared__ float acts[1280];
    const int c = blockIdx.x, bg = blockIdx.y;
    const int tid = threadIdx.x;
    for (int q = tid; q < 4096; q += 128) {
        const int b_l = q >> 9, rest = q & 511, il = rest >> 3, a = rest & 7;
        const int i = c * 64 + il, cap = i / 36, p = i - cap * 36;
        x3s[q] = x3m[((size_t)(bg * 8 + b_l) * 36 + p) * 256 + cap * 8 + a];
    }
    for (int q = tid; q < 1280; q += 128)
        acts[q] = act[(size_t)(bg * 8 + q / 160) * 160 + (q % 160)];
    __syncthreads();
    const int il = tid >> 1, half = tid & 1;
    const int i = c * 64 + il;
    #pragma unroll 1
    for (int oo = 0; oo < 5; ++oo) {
        const int o = half * 5 + oo;
        float s[8];
        #pragma unroll
        for (int b_l = 0; b_l < 8; ++b_l) s[b_l] = 0.f;
        #pragma unroll
        for (int a = 0; a < 8; ++a) {
            const uint4* dp = reinterpret_cast<const uint4*>(
                &dwb_t[(((size_t)i * 8 + a) * 10 + o) * 16]);
            uint4 d0 = dp[0], d1 = dp[1];
            const u32 du[8] = {d0.x, d0.y, d0.z, d0.w, d1.x, d1.y, d1.z, d1.w};
            #pragma unroll
            for (int b_l = 0; b_l < 8; ++b_l) {
                const float* ap = &acts[b_l * 160 + o * 16];
                float inner = 0.f;
                #pragma unroll
                for (int q = 0; q < 8; ++q) {
                    inner += __uint_as_float(du[q] << 16) * ap[2 * q];
                    inner += __uint_as_float(du[q] & 0xffff0000u) * ap[2 * q + 1];
                }
                s[b_l] += x3s[(b_l * 64 + il) * 8 + a] * inner;
            }
        }
        #pragma unroll
        for (int b_l = 0; b_l < 8; ++b_l) {
            float* lp = &logits[((size_t)(bg * 8 + b_l) * 1152 + i) * 10 + o];
            if (first) *lp = s[b_l]; else *lp += s[b_l];
        }
    }
}

// ============================================================
// Kernel 9: dense layer; 4 rows/block; mode 0=relu, 1=sigmoid,
// maskY != nullptr: input is act masked by y on the fly (K=160).
// ============================================================
__global__ __launch_bounds__(256) void mlp_layer(const float* __restrict__ in,
    const float* __restrict__ maskY, const float* __restrict__ w,
    const float* __restrict__ bias, float* __restrict__ outp, int K, int N, int mode)
{
    __shared__ float ins[4 * 1024];
    const int b0 = blockIdx.x * 4;
    const int n = blockIdx.y * 256 + threadIdx.x;
    for (int idx = threadIdx.x; idx < 4 * K; idx += 256) {
        float v = in[(size_t)b0 * K + idx];
        if (maskY) {
            const int b_l = idx / K, j = idx % K;
            v *= maskY[(b0 + b_l) * 10 + (j >> 4)];
        }
        ins[idx] = v;
    }
    __syncthreads();
    if (n < N) {
        float a0 = 0.f, a1 = 0.f, a2 = 0.f, a3 = 0.f;
        for (int k = 0; k < K; ++k) {
            const float wvv = w[(size_t)k * N + n];
            a0 += ins[k] * wvv;
            a1 += ins[K + k] * wvv;
            a2 += ins[2 * K + k] * wvv;
            a3 += ins[3 * K + k] * wvv;
        }
        const float bv = bias[n];
        float v[4] = {a0 + bv, a1 + bv, a2 + bv, a3 + bv};
        #pragma unroll
        for (int j = 0; j < 4; ++j) {
            float xv = v[j];
            xv = (mode == 0) ? fmaxf(xv, 0.f) : 1.f / (1.f + __expf(-xv));
            outp[(size_t)(b0 + j) * N + n] = xv;
        }
    }
}

// ============================================================
extern "C" void kernel_launch(void* const* d_in, const int* in_sizes, int n_in,
                              void* d_out, int out_size, void* d_ws, size_t ws_size,
                              hipStream_t stream) {
    const float* x   = (const float*)d_in[0];
    const float* y   = (const float*)d_in[1];
    const float* c1w = (const float*)d_in[2];
    const float* c1b = (const float*)d_in[3];
    const float* pw  = (const float*)d_in[4];
    const float* pb  = (const float*)d_in[5];
    const float* dw  = (const float*)d_in[6];
    const float* db  = (const float*)d_in[7];
    const float* w1  = (const float*)d_in[8];
    const float* b1  = (const float*)d_in[9];
    const float* w2  = (const float*)d_in[10];
    const float* b2  = (const float*)d_in[11];
    const float* w3  = (const float*)d_in[12];
    const float* b3  = (const float*)d_in[13];
    float* out = (float*)d_out;
    char* ws = (char*)d_ws;

    static const int exp_sizes[14] = {200704, 2560, 20736, 256, 5308416, 256,
                                      1474560, 160, 81920, 512, 524288, 1024,
                                      802816, 784};
    int bad = (n_in == 14) ? -1 : -2;
    if (bad == -1)
        for (int i = 0; i < 14; ++i) if (in_sizes[i] != exp_sizes[i]) { bad = i; break; }
    if (bad != -1) {
        fill_sentinel<<<(out_size + 255) / 256, 256, 0, stream>>>(out, out_size,
            7168.f + 16.f * (float)(bad + 1));
        return;
    }
    const size_t NEEDED = 72482816ULL;
    if (ws_size < NEEDED) {
        fill_sentinel<<<(out_size + 255) / 256, 256, 0, stream>>>(out, out_size, 111.0f);
        return;
    }

    // GEMM-phase live set: h + wT2 + x3m = 72.5 MB
    u16*   h       = (u16*)(ws);                    // [0, 52,428,800)
    u16*   wT2     = (u16*)(ws + 52428800);         // [52,428,800, 63,045,632)
    float* x3m     = (float*)(ws + 63045632);       // [63,045,632, 72,482,816)
    u16*   c1wb    = (u16*)(ws + 63045632);         // 41 KB inside x3m (dead pre-memset)
    // after GEMM, h/wT2 dead: routing/recon overlays
    float* logits  = (float*)(ws);                  // 11,796,480
    float* act     = (float*)(ws + 11796480);       //    163,840
    float* r1      = (float*)(ws + 11960320);       //    524,288
    float* r2      = (float*)(ws + 12484608);       //  1,048,576
    float* preactD = (float*)(ws + 13533184);       //  3 x 163,840 = 491,520
    u16*   dwb_t   = (u16*)(ws + 14024704);         //  2,949,120
    u16*   dwb_a   = (u16*)(ws + 16973824);         //  2,949,120 (ends 19.9 MB)

    conv_c1wb<<<81, 256, 0, stream>>>(c1w, c1wb);
    conv1_kernel<<<1024, 256, 0, stream>>>(x, c1wb, c1b, h);
    transpose_primw<<<256, 256, 0, stream>>>(pw, wT2);
    hipMemsetAsync(x3m, 0, 9437184, stream);        // also kills c1wb (dead)
    prim_gemm_noLDS<<<dim3(144, 8), 256, 0, stream>>>(h, wT2, x3m);
    squash_kernel<<<9216, 256, 0, stream>>>(x3m, pb);
    conv_dwb<<<5760, 256, 0, stream>>>(dw, dwb_t, dwb_a);
    hipMemsetAsync(preactD, 0, 491520, stream);     // all 3 iterations' buffers

    float* pD0 = preactD, *pD1 = preactD + 40960, *pD2 = preactD + 81920;
    // routing iter 1 (uniform), 2, 3
    routing_act_part<<<dim3(18, 32), 256, 0, stream>>>(x3m, dwb_a, logits, pD0, 1);
    routing_squash<<<256, 192, 0, stream>>>(pD0, db, act, (float*)nullptr);
    routing_upd_part<<<dim3(18, 32), 128, 0, stream>>>(x3m, dwb_t, act, logits, 1);

    routing_act_part<<<dim3(18, 32), 256, 0, stream>>>(x3m, dwb_a, logits, pD1, 0);
    routing_squash<<<256, 192, 0, stream>>>(pD1, db, act, (float*)nullptr);
    routing_upd_part<<<dim3(18, 32), 128, 0, stream>>>(x3m, dwb_t, act, logits, 0);

    routing_act_part<<<dim3(18, 32), 256, 0, stream>>>(x3m, dwb_a, logits, pD2, 0);
    routing_squash<<<256, 192, 0, stream>>>(pD2, db, act, out);

    // reconstruction (mask fused into first layer)
    mlp_layer<<<dim3(64, 2), 256, 0, stream>>>(act, y, w1, b1, r1, 160, 512, 0);
    mlp_layer<<<dim3(64, 4), 256, 0, stream>>>(r1, (float*)nullptr, w2, b2, r2, 512, 1024, 0);
    mlp_layer<<<dim3(64, 4), 256, 0, stream>>>(r2, (float*)nullptr, w3, b3, out + 40960, 1024, 784, 1);
}

// Round 11
// 774.439 us; speedup vs baseline: 1.4923x; 1.4923x over previous
//
#include <hip/hip_runtime.h>
#include <hip/hip_bf16.h>

typedef unsigned short u16;
typedef unsigned int u32;

static __device__ __forceinline__ float us2f(u16 u) {
    return __uint_as_float(((u32)u) << 16);
}
static __device__ __forceinline__ u16 f2bu(float f) {  // RNE
    u32 u = __float_as_uint(f);
    return (u16)((u + 0x7fffu + ((u >> 16) & 1u)) >> 16);
}

typedef __attribute__((ext_vector_type(8))) __bf16 bf16x8;
typedef __attribute__((ext_vector_type(4))) float f32x4;

__global__ void fill_sentinel(float* out, int n, float val) {
    int g = blockIdx.x * 256 + threadIdx.x;
    if (g < n) out[g] = val;
}

// ============================================================
// Kernel 0: conv1 weights f32 [c][j] -> bf16 [j][c]
// ============================================================
__global__ __launch_bounds__(256) void conv_c1wb(const float* __restrict__ w,
                                                 u16* __restrict__ wb)
{
    const int j = blockIdx.x, c = threadIdx.x;   // 81 x 256
    wb[j * 256 + c] = f2bu(w[c * 81 + j]);
}

// ============================================================
// Kernel 1: conv1 9x9 s1 + bias + relu -> h NHWC bf16 [B][20][20][256]
// ============================================================
__global__ __launch_bounds__(256) void conv1_kernel(const float* __restrict__ x,
    const u16* __restrict__ wb, const float* __restrict__ bias, u16* __restrict__ h)
{
    __shared__ float xs[784];
    __shared__ u16 wl[81 * 256];
    const int b = blockIdx.x >> 2, g = blockIdx.x & 3;
    const int c = threadIdx.x;
    for (int idx = c; idx < 784; idx += 256) xs[idx] = x[b * 784 + idx];
    for (int idx = c; idx < 20736; idx += 256) wl[idx] = wb[idx];
    __syncthreads();
    const float bv = bias[c];
    #pragma unroll 1
    for (int iy = g * 5; iy < g * 5 + 5; ++iy) {
        float acc[20];
        #pragma unroll
        for (int i = 0; i < 20; ++i) acc[i] = bv;
        #pragma unroll 1
        for (int dy = 0; dy < 9; ++dy) {
            float xr[28];
            const float4* xrow = reinterpret_cast<const float4*>(&xs[(iy + dy) * 28]);
            #pragma unroll
            for (int i = 0; i < 7; ++i) {
                float4 v = xrow[i];
                xr[4*i] = v.x; xr[4*i+1] = v.y; xr[4*i+2] = v.z; xr[4*i+3] = v.w;
            }
            #pragma unroll
            for (int dx = 0; dx < 9; ++dx) {
                const float wv = us2f(wl[(dy * 9 + dx) * 256 + c]);
                #pragma unroll
                for (int ix = 0; ix < 20; ++ix) acc[ix] += xr[ix + dx] * wv;
            }
        }
        u16* hp = h + ((b * 20 + iy) * 20) * 256 + c;
        #pragma unroll
        for (int ix = 0; ix < 20; ++ix) hp[ix * 256] = f2bu(fmaxf(acc[ix], 0.f));
    }
}

// ============================================================
// Kernel 2: transpose prim_w f32 [n][c][kyx] -> wT2 bf16 [n][kyx][c]
// ============================================================
__global__ __launch_bounds__(256) void transpose_primw(const float* __restrict__ w,
                                                       u16* __restrict__ wt)
{
    __shared__ u16 wl[81 * 258];
    const int n = blockIdx.x, tid = threadIdx.x;
    const float* ws = w + (size_t)n * 20736;
    for (int idx = tid; idx < 20736; idx += 256) {
        const int cc = idx / 81, kk = idx - cc * 81;
        wl[kk * 258 + cc] = f2bu(ws[idx]);
    }
    __syncthreads();
    u16* wo = wt + (size_t)n * 20736;
    for (int q = tid; q < 20736; q += 256)
        wo[q] = wl[(q >> 8) * 258 + (q & 255)];
}

// ============================================================
// Kernel 3: dw f32 -> bf16 [i][a][ot] (source order)
// ============================================================
__global__ __launch_bounds__(256) void conv_dwb(const float* __restrict__ dw,
                                                u16* __restrict__ dwb_t)
{
    const int g = blockIdx.x * 256 + threadIdx.x;   // 1,474,560
    dwb_t[g] = f2bu(dw[g]);
}

// ============================================================
// Kernel 4: primary-caps GEMM — r9 validated (split-K=12, BK=32, pad-40)
// ============================================================
__global__ __launch_bounds__(256) void prim_gemm_split(const u16* __restrict__ h,
    const u16* __restrict__ wT, float* __restrict__ pm)
{
    __shared__ u16 As[128 * 40];
    __shared__ u16 Bs[128 * 40];
    const int tid = threadIdx.x;
    const int split = blockIdx.y;
    const int mt = blockIdx.x % 72, nt = blockIdx.x / 72;
    const int mBase = mt * 128, nBase = nt * 128;
    const int tq = tid & 3, tr = tid >> 2;
    int m0 = mBase + tr;
    int b0 = m0 / 36, r0 = m0 % 36;
    int aBase0 = ((b0 * 20 + 2 * (r0 / 6)) * 20 + 2 * (r0 % 6)) * 256 + tq * 8;
    int m1 = m0 + 64;
    int b1 = m1 / 36, r1 = m1 % 36;
    int aBase1 = ((b1 * 20 + 2 * (r1 / 6)) * 20 + 2 * (r1 % 6)) * 256 + tq * 8;
    const int bBase0 = (nBase + tr) * 20736 + tq * 8;
    const int bBase1 = (nBase + tr + 64) * 20736 + tq * 8;
    int kglob = split * 1728;
    int ky = kglob / 2304; int krem = kglob - ky * 2304;
    int kx = krem >> 8; int c0 = krem & 255;

    f32x4 acc[4][4];
    #pragma unroll
    for (int i = 0; i < 4; ++i)
        #pragma unroll
        for (int j = 0; j < 4; ++j) acc[i][j] = (f32x4){0.f, 0.f, 0.f, 0.f};

    const int lane = tid & 63;
    const int wvi = tid >> 6; const int wm = wvi >> 1, wn = wvi & 1;
    const int lcol = lane & 15, lquad = lane >> 4;
    const u16* Arow = As + (wm * 64 + lcol) * 40 + lquad * 8;
    const u16* Brow = Bs + (wn * 64 + lcol) * 40 + lquad * 8;

    #pragma unroll 1
    for (int kt = 0; kt < 54; ++kt) {
        const int koffA = (ky * 20 + kx) * 256 + c0;
        uint4 ra0 = *reinterpret_cast<const uint4*>(h + aBase0 + koffA);
        uint4 ra1 = *reinterpret_cast<const uint4*>(h + aBase1 + koffA);
        uint4 rb0 = *reinterpret_cast<const uint4*>(wT + bBase0 + kglob);
        uint4 rb1 = *reinterpret_cast<const uint4*>(wT + bBase1 + kglob);
        __syncthreads();
        *reinterpret_cast<uint4*>(As + tr * 40 + tq * 8)        = ra0;
        *reinterpret_cast<uint4*>(As + (tr + 64) * 40 + tq * 8) = ra1;
        *reinterpret_cast<uint4*>(Bs + tr * 40 + tq * 8)        = rb0;
        *reinterpret_cast<uint4*>(Bs + (tr + 64) * 40 + tq * 8) = rb1;
        __syncthreads();
        bf16x8 af[4], bfr[4];
        #pragma unroll
        for (int i = 0; i < 4; ++i)
            af[i] = *reinterpret_cast<const bf16x8*>(Arow + i * 640);
        #pragma unroll
        for (int j = 0; j < 4; ++j)
            bfr[j] = *reinterpret_cast<const bf16x8*>(Brow + j * 640);
        #pragma unroll
        for (int i = 0; i < 4; ++i)
            #pragma unroll
            for (int j = 0; j < 4; ++j)
                acc[i][j] = __builtin_amdgcn_mfma_f32_16x16x32_bf16(af[i], bfr[j], acc[i][j], 0, 0, 0);
        kglob += 32; c0 += 32;
        if (c0 == 256) { c0 = 0; if (++kx == 9) { kx = 0; ++ky; } }
    }
    #pragma unroll
    for (int i = 0; i < 4; ++i) {
        const int mrow = mBase + wm * 64 + i * 16 + lquad * 4;
        #pragma unroll
        for (int j = 0; j < 4; ++j) {
            const int ncol = nBase + wn * 64 + j * 16 + lcol;
            #pragma unroll
            for (int r = 0; r < 4; ++r)
                unsafeAtomicAdd(&pm[(size_t)(mrow + r) * 256 + ncol], acc[i][j][r]);
        }
    }
}

// ============================================================
// Kernel 5: in-place /32 + prim_b + squash (row-local)
// ============================================================
__global__ __launch_bounds__(256) void squash_kernel(float* __restrict__ pm,
    const float* __restrict__ pb)
{
    const int m = blockIdx.x, t = threadIdx.x;
    float pre = pm[(size_t)m * 256 + t] * (1.f / 32.f) + pb[t];
    float sq = pre * pre;
    sq += __shfl_xor(sq, 1); sq += __shfl_xor(sq, 2); sq += __shfl_xor(sq, 4);
    float scale = (sq / (1.f + sq)) * rsqrtf(sq + 1e-9f);
    pm[(size_t)m * 256 + t] = pre * scale;
}

// ============================================================
// Kernel 6: votes materialization (per batch-half).
// votes[b_l][ot][i] (bf16) = sum_a x3[hb+b_l][i][a] * dw[i][a][ot]
// grid (144 i-chunks of 8, 2 b-chunks of 64), block 192 (160 compute).
// ============================================================
__global__ __launch_bounds__(192) void votes_gemm(const float* __restrict__ x3m,
    const u16* __restrict__ dwb_t, u16* __restrict__ votes, int hb)
{
    __shared__ float dws[8 * 1280];    // [i_l][a][ot] 40 KB
    __shared__ float x3s[64 * 64];     // [b_l][i_l][a] 16 KB
    const int ic = blockIdx.x * 8, bc = blockIdx.y * 64;
    const int tid = threadIdx.x;
    for (int q = tid; q < 10240; q += 192)
        dws[q] = us2f(dwb_t[(size_t)ic * 1280 + q]);
    for (int q = tid; q < 4096; q += 192) {
        const int b_l = q >> 6, r = q & 63, i_l = r >> 3, a = r & 7;
        const int i = ic + i_l, cap = i / 36, p = i - cap * 36;
        x3s[q] = x3m[((size_t)(hb + bc + b_l) * 36 + p) * 256 + cap * 8 + a];
    }
    __syncthreads();
    if (tid < 160) {
        const int ot = tid;
        float dwr[8][8];
        #pragma unroll
        for (int i_l = 0; i_l < 8; ++i_l)
            #pragma unroll
            for (int a = 0; a < 8; ++a)
                dwr[i_l][a] = dws[i_l * 1280 + a * 160 + ot];
        #pragma unroll 1
        for (int b_l = 0; b_l < 64; ++b_l) {
            u16 ob[8];
            #pragma unroll
            for (int i_l = 0; i_l < 8; ++i_l) {
                const float* xp = &x3s[b_l * 64 + i_l * 8];
                float v = 0.f;
                #pragma unroll
                for (int a = 0; a < 8; ++a) v += xp[a] * dwr[i_l][a];
                ob[i_l] = f2bu(v);
            }
            uint4 o4;
            o4.x = (u32)ob[0] | ((u32)ob[1] << 16);
            o4.y = (u32)ob[2] | ((u32)ob[3] << 16);
            o4.z = (u32)ob[4] | ((u32)ob[5] << 16);
            o4.w = (u32)ob[6] | ((u32)ob[7] << 16);
            *reinterpret_cast<uint4*>(&votes[((size_t)(bc + b_l) * 160 + ot) * 1152 + ic]) = o4;
        }
    }
}

// ============================================================
// Kernel 7: routing act pass over materialized votes.
// preactD[gb][ot] += sum_i route[gb][i][o] * votes[b_l][ot][i]
// grid (3 i-chunks of 384, 128 b_l), block 256. LDS votes tile pad-65.
// ============================================================
__global__ __launch_bounds__(256) void routing_act3(const u16* __restrict__ votes,
    const float* __restrict__ logits, float* __restrict__ preactD, int hb, int uniform)
{
    __shared__ float route_s[384 * 10];   // 15,360 B
    __shared__ float vs[160 * 65];        // 41,600 B
    const int ic = blockIdx.x * 384, b_l = blockIdx.y;
    const int gb = hb + b_l;
    const int tid = threadIdx.x;
    if (!uniform) {
        for (int q = tid; q < 384; q += 256) {
            const float* lg = &logits[((size_t)gb * 1152 + ic + q) * 10];
            float l[10]; float mx = -1e30f;
            #pragma unroll
            for (int k = 0; k < 10; ++k) { l[k] = lg[k]; mx = fmaxf(mx, l[k]); }
            float s = 0.f;
            #pragma unroll
            for (int k = 0; k < 10; ++k) { l[k] = __expf(l[k] - mx); s += l[k]; }
            const float inv = 1.f / s;
            #pragma unroll
            for (int k = 0; k < 10; ++k) route_s[q * 10 + k] = l[k] * inv;
        }
    }
    float acc = 0.f;
    const int o = (tid & 255) >> 4;
    #pragma unroll 1
    for (int sc = 0; sc < 6; ++sc) {
        __syncthreads();
        for (int q = tid; q < 1280; q += 256) {
            const int ot = q >> 3, i8 = q & 7;
            const uint4 d = *reinterpret_cast<const uint4*>(
                &votes[((size_t)b_l * 160 + ot) * 1152 + ic + sc * 64 + i8 * 8]);
            const u32 du[4] = {d.x, d.y, d.z, d.w};
            float* vp = &vs[ot * 65 + i8 * 8];
            #pragma unroll
            for (int k = 0; k < 4; ++k) {
                vp[2 * k]     = __uint_as_float(du[k] << 16);
                vp[2 * k + 1] = __uint_as_float(du[k] & 0xffff0000u);
            }
        }
        __syncthreads();
        if (tid < 160) {
            const float* vrow = &vs[tid * 65];
            if (uniform) {
                float s = 0.f;
                #pragma unroll
                for (int il = 0; il < 64; ++il) s += vrow[il];
                acc += 0.1f * s;
            } else {
                const float* rp = &route_s[sc * 640 + o];   // (sc*64+il)*10 + o
                #pragma unroll
                for (int il = 0; il < 64; ++il)
                    acc += rp[il * 10] * vrow[il];
            }
        }
    }
    if (tid < 160)
        unsafeAtomicAdd(&preactD[(size_t)gb * 160 + tid], acc);
}

// ============================================================
// Kernel 8: preactD + digit_b -> squash -> act (+digit out). grid 128/half.
// ============================================================
__global__ __launch_bounds__(192) void routing_squash(const float* __restrict__ preactD,
    const float* __restrict__ db, float* __restrict__ act, float* __restrict__ dout, int hb)
{
    const int b = hb + blockIdx.x, tid = threadIdx.x;
    if (tid < 160) {
        float pre = preactD[(size_t)b * 160 + tid] + db[tid];
        float sq = pre * pre;
        sq += __shfl_xor(sq, 1); sq += __shfl_xor(sq, 2);
        sq += __shfl_xor(sq, 4); sq += __shfl_xor(sq, 8);
        float scale = (sq / (1.f + sq)) * rsqrtf(sq + 1e-9f);
        float a = pre * scale;
        act[(size_t)b * 160 + tid] = a;
        if (dout) dout[(size_t)b * 160 + tid] = a;
    }
}

// ============================================================
// Kernel 9: logits update over votes.
// logits[gb][i][o] (+)= sum_t votes[b_l][o*16+t][i] * act[gb][o*16+t]
// grid (9 i-chunks of 128, 128 b_l), block 128 (thread = i).
// ============================================================
__global__ __launch_bounds__(128) void routing_upd3(const u16* __restrict__ votes,
    const float* __restrict__ act, float* __restrict__ logits, int hb, int first)
{
    __shared__ float act_s[160];
    const int b_l = blockIdx.y, gb = hb + b_l;
    const int i = blockIdx.x * 128 + threadIdx.x;
    for (int q = threadIdx.x; q < 160; q += 128)
        act_s[q] = act[(size_t)gb * 160 + q];
    __syncthreads();
    float acc[10];
    #pragma unroll
    for (int k = 0; k < 10; ++k) acc[k] = 0.f;
    const u16* vb = &votes[(size_t)b_l * 160 * 1152 + i];
    #pragma unroll
    for (int ot = 0; ot < 160; ++ot)
        acc[ot >> 4] += us2f(vb[(size_t)ot * 1152]) * act_s[ot];
    float* lp = &logits[((size_t)gb * 1152 + i) * 10];
    if (first) {
        #pragma unroll
        for (int k = 0; k < 10; ++k) lp[k] = acc[k];
    } else {
        #pragma unroll
        for (int k = 0; k < 10; ++k) lp[k] += acc[k];
    }
}

// ============================================================
// Kernel 10: dense layer; 4 rows/block; mask fused when maskY != nullptr
// ============================================================
__global__ __launch_bounds__(256) void mlp_layer(const float* __restrict__ in,
    const float* __restrict__ maskY, const float* __restrict__ w,
    const float* __restrict__ bias, float* __restrict__ outp, int K, int N, int mode)
{
    __shared__ float ins[4 * 1024];
    const int b0 = blockIdx.x * 4;
    const int n = blockIdx.y * 256 + threadIdx.x;
    for (int idx = threadIdx.x; idx < 4 * K; idx += 256) {
        float v = in[(size_t)b0 * K + idx];
        if (maskY) {
            const int b_l = idx / K, j = idx % K;
            v *= maskY[(b0 + b_l) * 10 + (j >> 4)];
        }
        ins[idx] = v;
    }
    __syncthreads();
    if (n < N) {
        float a0 = 0.f, a1 = 0.f, a2 = 0.f, a3 = 0.f;
        for (int k = 0; k < K; ++k) {
            const float wvv = w[(size_t)k * N + n];
            a0 += ins[k] * wvv;
            a1 += ins[K + k] * wvv;
            a2 += ins[2 * K + k] * wvv;
            a3 += ins[3 * K + k] * wvv;
        }
        const float bv = bias[n];
        float v[4] = {a0 + bv, a1 + bv, a2 + bv, a3 + bv};
        #pragma unroll
        for (int j = 0; j < 4; ++j) {
            float xv = v[j];
            xv = (mode == 0) ? fmaxf(xv, 0.f) : 1.f / (1.f + __expf(-xv));
            outp[(size_t)(b0 + j) * N + n] = xv;
        }
    }
}

// ============================================================
extern "C" void kernel_launch(void* const* d_in, const int* in_sizes, int n_in,
                              void* d_out, int out_size, void* d_ws, size_t ws_size,
                              hipStream_t stream) {
    const float* x   = (const float*)d_in[0];
    const float* y   = (const float*)d_in[1];
    const float* c1w = (const float*)d_in[2];
    const float* c1b = (const float*)d_in[3];
    const float* pw  = (const float*)d_in[4];
    const float* pb  = (const float*)d_in[5];
    const float* dw  = (const float*)d_in[6];
    const float* db  = (const float*)d_in[7];
    const float* w1  = (const float*)d_in[8];
    const float* b1  = (const float*)d_in[9];
    const float* w2  = (const float*)d_in[10];
    const float* b2  = (const float*)d_in[11];
    const float* w3  = (const float*)d_in[12];
    const float* b3  = (const float*)d_in[13];
    float* out = (float*)d_out;
    char* ws = (char*)d_ws;

    static const int exp_sizes[14] = {200704, 2560, 20736, 256, 5308416, 256,
                                      1474560, 160, 81920, 512, 524288, 1024,
                                      802816, 784};
    int bad = (n_in == 14) ? -1 : -2;
    if (bad == -1)
        for (int i = 0; i < 14; ++i) if (in_sizes[i] != exp_sizes[i]) { bad = i; break; }
    if (bad != -1) {
        fill_sentinel<<<(out_size + 255) / 256, 256, 0, stream>>>(out, out_size,
            7168.f + 16.f * (float)(bad + 1));
        return;
    }
    const size_t NEEDED = 72482816ULL;
    if (ws_size < NEEDED) {
        fill_sentinel<<<(out_size + 255) / 256, 256, 0, stream>>>(out, out_size, 111.0f);
        return;
    }

    // Phase A (conv/GEMM): h + wT2 + x3m
    u16*   h       = (u16*)(ws);                    // [0, 52,428,800)
    u16*   wT2     = (u16*)(ws + 52428800);         // [52,428,800, 63,045,632)
    float* x3m     = (float*)(ws + 63045632);       // [63,045,632, 72,482,816)
    u16*   c1wb    = (u16*)(ws + 63045632);         // 41 KB inside x3m (dead pre-memset)
    // Phase B (routing/recon), h/wT2 dead:
    u16*   votes   = (u16*)(ws);                    // 47,185,920
    float* logits  = (float*)(ws + 47185920);       // 11,796,480 -> 58,982,400
    float* act     = (float*)(ws + 58982400);       //    163,840 -> 59,146,240
    float* preactD = (float*)(ws + 59146240);       //  3x163,840 -> 59,637,760
    u16*   dwb_t   = (u16*)(ws + 59637760);         //  2,949,120 -> 62,586,880
    float* r1      = (float*)(ws + 62586880);       //    524,288 -> 63,111,168 (post-routing)
    float* r2      = (float*)(ws + 63111168);       //  1,048,576 -> 64,159,744 (post-routing)

    conv_c1wb<<<81, 256, 0, stream>>>(c1w, c1wb);
    conv1_kernel<<<1024, 256, 0, stream>>>(x, c1wb, c1b, h);
    transpose_primw<<<256, 256, 0, stream>>>(pw, wT2);
    hipMemsetAsync(x3m, 0, 9437184, stream);
    prim_gemm_split<<<dim3(144, 12), 256, 0, stream>>>(h, wT2, x3m);
    squash_kernel<<<9216, 256, 0, stream>>>(x3m, pb);
    conv_dwb<<<5760, 256, 0, stream>>>(dw, dwb_t);
    hipMemsetAsync(preactD, 0, 491520, stream);

    float* pD0 = preactD, *pD1 = preactD + 40960, *pD2 = preactD + 81920;
    for (int half = 0; half < 2; ++half) {
        const int hb = half * 128;
        votes_gemm<<<dim3(144, 2), 192, 0, stream>>>(x3m, dwb_t, votes, hb);
        // iter 1 (uniform), 2, 3
        routing_act3<<<dim3(3, 128), 256, 0, stream>>>(votes, logits, pD0, hb, 1);
        routing_squash<<<128, 192, 0, stream>>>(pD0, db, act, (float*)nullptr, hb);
        routing_upd3<<<dim3(9, 128), 128, 0, stream>>>(votes, act, logits, hb, 1);
        routing_act3<<<dim3(3, 128), 256, 0, stream>>>(votes, logits, pD1, hb, 0);
        routing_squash<<<128, 192, 0, stream>>>(pD1, db, act, (float*)nullptr, hb);
        routing_upd3<<<dim3(9, 128), 128, 0, stream>>>(votes, act, logits, hb, 0);
        routing_act3<<<dim3(3, 128), 256, 0, stream>>>(votes, logits, pD2, hb, 0);
        routing_squash<<<128, 192, 0, stream>>>(pD2, db, act, out, hb);
    }

    // reconstruction
    mlp_layer<<<dim3(64, 2), 256, 0, stream>>>(act, y, w1, b1, r1, 160, 512, 0);
    mlp_layer<<<dim3(64, 4), 256, 0, stream>>>(r1, (float*)nullptr, w2, b2, r2, 512, 1024, 0);
    mlp_layer<<<dim3(64, 4), 256, 0, stream>>>(r2, (float*)nullptr, w3, b3, out + 40960, 1024, 784, 1);
}